// Round 11
// baseline (1066.642 us; speedup 1.0000x reference)
//
#include <hip/hip_runtime.h>
#include <hip/hip_bf16.h>

// ---------------------------------------------------------------------------
// UNet3D dense forward, round 11: NDHWC implicit-GEMM MFMA.
//  - T14 reg-staging pipeline: per ci-chunk, next chunk's global loads are
//    issued into registers right after the barrier and fly under the MFMA
//    compute of the current chunk (write->LDS happens next iteration).
//  - Applied to V0 stride-1 convs and quadrant tconvs. BN fused at LDS-write
//    (halo validity re-derived so padding stays zero).
//  - conv2: CO_TILES=1, y=8 (256 workgroups, was 128 -> half GPU idle).
//  - tconv1c: back to CO_TILES=2, y=2 (+pipeline) to avoid VGPR pressure.
// ---------------------------------------------------------------------------

using bf16 = __hip_bfloat16;
using ushort4v = __attribute__((ext_vector_type(4))) unsigned short;
using ushort8  = __attribute__((ext_vector_type(8))) unsigned short;
using short8   = __attribute__((ext_vector_type(8))) short;
using f32x4    = __attribute__((ext_vector_type(4))) float;
using float4v  = __attribute__((ext_vector_type(4))) float;

#define TPB 256

static inline int cdiv_l(long a, int b){ return (int)((a + b - 1) / b); }

__device__ __forceinline__ float b2f(unsigned short u){
  union { unsigned int i; float f; } v; v.i = ((unsigned int)u) << 16; return v.f;
}
__device__ __forceinline__ unsigned short f2b(float f){
  union { bf16 h; unsigned short u; } v; v.h = __float2bfloat16(f); return v.u;
}
// BN+ReLU on 8 packed bf16 channels starting at channel c (8-aligned).
__device__ __forceinline__ ushort8 bnApply8(ushort8 v, const float* sc, const float* sh, int c){
  float4v s0 = *(const float4v*)(sc + c), s1v = *(const float4v*)(sc + c + 4);
  float4v h0 = *(const float4v*)(sh + c), h1v = *(const float4v*)(sh + c + 4);
  ushort8 r;
#pragma unroll
  for (int j = 0; j < 4; ++j){ float y = b2f(v[j]) * s0[j] + h0[j]; r[j] = f2b(y > 0.f ? y : 0.f); }
#pragma unroll
  for (int j = 0; j < 4; ++j){ float y = b2f(v[j+4]) * s1v[j] + h1v[j]; r[j+4] = f2b(y > 0.f ? y : 0.f); }
  return r;
}

// ---------------- weight repacks (bf16) ----------------
__global__ void rp_enc(const float* __restrict__ w, unsigned short* __restrict__ wb,
                       int Cin, int Cout){
  int idx = blockIdx.x * TPB + threadIdx.x;
  int tot = 27 * Cout * Cin; if (idx >= tot) return;
  int ci = idx % Cin; int t = idx / Cin; int co = t % Cout; int tap = t / Cout;
  wb[idx] = f2b(w[((long)co * Cin + ci) * 27 + tap]);
}
__global__ void rp_dec(const float* __restrict__ w, unsigned short* __restrict__ wb,
                       int Cin, int Cout, int CIP, int COP){
  int idx = blockIdx.x * TPB + threadIdx.x;
  int tot = 27 * COP * CIP; if (idx >= tot) return;
  int ci = idx % CIP; int t = idx / CIP; int co = t % COP; int tap = t / COP;
  float v = (ci < Cin && co < Cout) ? w[((long)tap * Cin + ci) * Cout + co] : 0.f;
  wb[idx] = f2b(v);
}
// conv0 tap-paired: [pp<14][co<32][k<32]
__global__ void rp_pair(const float* __restrict__ w, unsigned short* __restrict__ wb){
  int idx = blockIdx.x * TPB + threadIdx.x;
  int tot = 14 * 32 * 32; if (idx >= tot) return;
  int k = idx & 31; int t = idx >> 5; int co = t & 31; int pp = t >> 5;
  int tap = pp * 2 + (k >> 4); int ci = k & 15;
  float v = (tap < 27) ? w[((long)co * 16 + ci) * 27 + tap] : 0.f;
  wb[idx] = f2b(v);
}

// ---------------- x transpose: NCDHW fp32 -> NDHWC bf16 (C=16) ----------------
__global__ void xpose_k(const float* __restrict__ x, unsigned short* __restrict__ xt){
  __shared__ float l[16][257];
  int t = threadIdx.x;
  long p0 = (long)blockIdx.x * 256;
  int n = (int)(p0 >> 18);
  long off = p0 & 262143;
  const float* xb = x + ((long)n * 16) * 262144 + off;
#pragma unroll
  for (int c = 0; c < 16; ++c) l[c][t] = xb[(long)c * 262144 + t];
  __syncthreads();
  ushort8 u0, u1;
#pragma unroll
  for (int k = 0; k < 8; ++k){ u0[k] = f2b(l[k][t]); u1[k] = f2b(l[k + 8][t]); }
  unsigned short* o = xt + (p0 + t) * 16;
  *(ushort8*)o = u0; *(ushort8*)(o + 8) = u1;
}

// ---------------- quadrant stride-2 tconv, LDS-staged, reg-pipelined -------
template <int CO_TILES>
__global__ __launch_bounds__(TPB, 2) void tconv_quad(
    const unsigned short* __restrict__ inA, int CA,
    const unsigned short* __restrict__ inB, int CB,
    const float* __restrict__ scA, const float* __restrict__ shA,
    const unsigned short* __restrict__ wb,
    unsigned short* __restrict__ out,
    int N, int Cout, int COP, int CIP, int G) {
  __shared__ unsigned short xs[4 * 432 * 8];
  constexpr int TOT = 4 * 425, NIT = (TOT + TPB - 1) / TPB;   // 7
  const int tid = threadIdx.x, wv = tid >> 6, l = tid & 63, l15 = l & 15, lg = l >> 4;
  int ntW = G >> 4, ntH = G >> 2, ntD = G >> 2;
  int bx = blockIdx.x;
  int w0 = (bx % ntW) << 4; bx /= ntW;
  int h0 = (bx % ntH) << 2; bx /= ntH;
  int d0 = (bx % ntD) << 2; int n = bx / ntD;
  const int co0 = blockIdx.y * (16 * CO_TILES);
  const int quad = blockIdx.z;
  const int pd = (quad >> 1) & 1, ph = quad & 1;
  const long spin = (long)G * G * G;

  int nkd, kd_[2], dd_[2], nkh, kh_[2], dh_[2];
  if (pd){ nkd=1; kd_[0]=1; dd_[0]=0; } else { nkd=2; kd_[0]=0; dd_[0]=-1; kd_[1]=2; dd_[1]=0; }
  if (ph){ nkh=1; kh_[0]=1; dh_[0]=0; } else { nkh=2; kh_[0]=0; dh_[0]=-1; kh_[1]=2; dh_[1]=0; }

  f32x4 acc[CO_TILES][4][2];
#pragma unroll
  for (int ct = 0; ct < CO_TILES; ++ct)
#pragma unroll
    for (int j = 0; j < 4; ++j)
#pragma unroll
      for (int p = 0; p < 2; ++p) acc[ct][j][p] = (f32x4){0.f, 0.f, 0.f, 0.f};

  ushort8 rA[NIT];
  auto loadChunk = [&](int c0) {
    const unsigned short* sb; int Cs, cl_;
    if (c0 < CA){ sb = inA + (long)n * CA * spin; Cs = CA; cl_ = c0; }
    else        { sb = inB + (long)n * CB * spin; Cs = CB; cl_ = c0 - CA; }
#pragma unroll
    for (int it = 0; it < NIT; ++it) {
      int idx = tid + it * TPB;
      ushort8 v = (ushort8){0,0,0,0,0,0,0,0};
      if (idx < TOT) {
        int q = idx / 425, pt = idx - q * 425;
        int zw = pt % 17; int zt = pt / 17; int zh = zt % 5; int zd = zt / 5;
        int gd = d0 + zd - 1, gh = h0 + zh - 1, gw = w0 + zw - 1;
        if ((unsigned)gd < (unsigned)G && (unsigned)gh < (unsigned)G && (unsigned)gw < (unsigned)G)
          v = *(const ushort8*)(sb + (((long)gd * G + gh) * G + gw) * Cs + cl_ + q * 8);
      }
      rA[it] = v;
    }
  };
  auto writeChunk = [&](int c0) {
    bool useBN; int cl_;
    if (c0 < CA){ useBN = (scA != nullptr); cl_ = c0; }
    else        { useBN = false; cl_ = c0 - CA; }
#pragma unroll
    for (int it = 0; it < NIT; ++it) {
      int idx = tid + it * TPB;
      if (idx < TOT) {
        int q = idx / 425, pt = idx - q * 425;
        ushort8 v = rA[it];
        if (useBN) {
          int zw = pt % 17; int zt = pt / 17; int zh = zt % 5; int zd = zt / 5;
          int gd = d0 + zd - 1, gh = h0 + zh - 1, gw = w0 + zw - 1;
          if ((unsigned)gd < (unsigned)G && (unsigned)gh < (unsigned)G && (unsigned)gw < (unsigned)G)
            v = bnApply8(v, scA, shA, cl_ + q * 8);
        }
        *(ushort8*)(xs + (q * 432 + pt) * 8) = v;
      }
    }
  };

  const int nch = CIP >> 5;
  loadChunk(0);
#pragma unroll 1
  for (int ch = 0; ch < nch; ++ch) {
    int c0 = ch << 5;
    if (ch) __syncthreads();
    writeChunk(c0);
    __syncthreads();
    if (ch + 1 < nch) loadChunk((ch + 1) << 5);
#pragma unroll 1
    for (int a = 0; a < nkd; ++a) {
      int zd = wv + 1 + dd_[a];
#pragma unroll 1
      for (int b = 0; b < nkh; ++b) {
        int tapb = (kd_[a] * 3 + kh_[b]) * 3;
        const unsigned short* ap = wb + ((long)tapb * COP + co0 + l15) * CIP + c0 + lg * 8;
        long tstride = (long)COP * CIP;
        short8 Ak0[CO_TILES], Ak1[CO_TILES], Ak2[CO_TILES];
#pragma unroll
        for (int ct = 0; ct < CO_TILES; ++ct) {
          Ak0[ct] = *(const short8*)(ap + ct * 16 * CIP);
          Ak1[ct] = *(const short8*)(ap + tstride + ct * 16 * CIP);
          Ak2[ct] = *(const short8*)(ap + 2 * tstride + ct * 16 * CIP);
        }
        int zh0 = 1 + dh_[b];
#pragma unroll
        for (int j = 0; j < 4; ++j) {
          int basept = (zd * 5 + (j + zh0)) * 17 + l15;
          short8 Bm = *(const short8*)(xs + (lg * 432 + basept) * 8);
          short8 B0 = *(const short8*)(xs + (lg * 432 + basept + 1) * 8);
#pragma unroll
          for (int ct = 0; ct < CO_TILES; ++ct) {
            acc[ct][j][0] = __builtin_amdgcn_mfma_f32_16x16x32_bf16(Ak0[ct], Bm, acc[ct][j][0], 0, 0, 0);
            acc[ct][j][0] = __builtin_amdgcn_mfma_f32_16x16x32_bf16(Ak2[ct], B0, acc[ct][j][0], 0, 0, 0);
            acc[ct][j][1] = __builtin_amdgcn_mfma_f32_16x16x32_bf16(Ak1[ct], B0, acc[ct][j][1], 0, 0, 0);
          }
        }
      }
    }
  }

  // ---- dense store ----
  int Gout = 2 * G; long spo = (long)Gout * Gout * Gout;
  int od = 2 * (d0 + wv) + pd;
#pragma unroll
  for (int j = 0; j < 4; ++j) {
    int oh = 2 * (h0 + j) + ph;
#pragma unroll
    for (int p = 0; p < 2; ++p) {
      int ow = 2 * (w0 + l15) + p;
      long pt = ((long)od * Gout + oh) * Gout + ow;
#pragma unroll
      for (int ct = 0; ct < CO_TILES; ++ct) {
        ushort4v pk;
#pragma unroll
        for (int r = 0; r < 4; ++r) pk[r] = f2b(acc[ct][j][p][r]);
        *(ushort4v*)(out + ((long)n * spo + pt) * Cout + co0 + ct * 16 + lg * 4) = pk;
      }
    }
  }
}

// ---------------- unified NDHWC MFMA conv ----------------
// VARIANT 0 / PAIRED: stride-1 conv, LDS-staged (reg-pipelined), 2d x 8h x 16w.
// VARIANT 2: stride-2 conv, direct-global B, 4d x 4h x 16w.
template <int VARIANT, int CO_TILES, bool PAIRED, bool FOUT>
__global__ __launch_bounds__(TPB) void mconv(
    const unsigned short* __restrict__ inA, int CA,
    const unsigned short* __restrict__ inB, int CB,
    const float* __restrict__ scA, const float* __restrict__ shA,
    const unsigned short* __restrict__ wb,
    void* __restrict__ outv,
    int N, int Cout, int COP, int CIP, int G) {
  const int tid = threadIdx.x, wv = tid >> 6, l = tid & 63, l15 = l & 15, lg = l >> 4;
  int bx = blockIdx.x;
  int w0, h0, d0, n;
  int wvd = wv & 1, jh = wv >> 1, jbase = jh * 4;
  if constexpr (VARIANT == 0) {
    int ntW = G >> 4, ntH = G >> 3, ntD = G >> 1;
    w0 = (bx % ntW) << 4; bx /= ntW;
    h0 = (bx % ntH) << 3; bx /= ntH;
    d0 = (bx % ntD) << 1; n = bx / ntD;
  } else {
    int ntW = G >> 4, ntH = G >> 2, ntD = G >> 2;
    w0 = (bx % ntW) << 4; bx /= ntW;
    h0 = (bx % ntH) << 2; bx /= ntH;
    d0 = (bx % ntD) << 2; n = bx / ntD;
  }
  const int co0 = blockIdx.y * (16 * CO_TILES);
  const int Gin = (VARIANT == 2) ? 2 * G : G;
  const long spin = (long)Gin * Gin * Gin;

  f32x4 acc[CO_TILES][4];
#pragma unroll
  for (int ct = 0; ct < CO_TILES; ++ct)
#pragma unroll
    for (int j = 0; j < 4; ++j) acc[ct][j] = (f32x4){0.f, 0.f, 0.f, 0.f};

  if constexpr (PAIRED) {
    // conv0: Cin=16, K packs 2 taps; raw input (no BN).
    __shared__ unsigned short xs[2 * 728 * 8];
    const unsigned short* src = inA + (long)n * 16 * spin;
    for (int idx = tid; idx < 2 * 720; idx += TPB) {
      int q = idx / 720, pt = idx - q * 720;
      int zw = pt % 18; int zt = pt / 18; int zh = zt % 10; int zd = zt / 10;
      int gd = d0 + zd - 1, gh = h0 + zh - 1, gw = w0 + zw - 1;
      ushort8 v = (ushort8){0,0,0,0,0,0,0,0};
      if ((unsigned)gd < (unsigned)G && (unsigned)gh < (unsigned)G && (unsigned)gw < (unsigned)G)
        v = *(const ushort8*)(src + (((long)gd * G + gh) * G + gw) * 16 + q * 8);
      *(ushort8*)(xs + (q * 728 + pt) * 8) = v;
    }
    __syncthreads();
#pragma unroll 1
    for (int pp = 0; pp < 14; ++pp) {
      short8 A0 = *(const short8*)(wb + ((pp * 32 + l15) * 32) + lg * 8);
      short8 A1 = *(const short8*)(wb + ((pp * 32 + 16 + l15) * 32) + lg * 8);
      int t0 = 2 * pp + (lg >> 1); if (t0 > 26) t0 = 26;
      int dd = t0 / 9 - 1, dh = (t0 / 3) % 3 - 1, dw = t0 % 3 - 1;
      int q = lg & 1;
      int zd = wvd + 1 + dd;
      int base = (q * 728 + (zd * 10 + (1 + dh + jbase)) * 18 + 1 + l15 + dw) * 8;
#pragma unroll
      for (int j = 0; j < 4; ++j) {
        short8 B = *(const short8*)(xs + base + j * (18 * 8));
        acc[0][j] = __builtin_amdgcn_mfma_f32_16x16x32_bf16(A0, B, acc[0][j], 0, 0, 0);
        if (CO_TILES == 2)
          acc[1][j] = __builtin_amdgcn_mfma_f32_16x16x32_bf16(A1, B, acc[1][j], 0, 0, 0);
      }
    }
  } else if constexpr (VARIANT == 0) {
    // stride-1 conv: s=b+j row-sharing; reg-pipelined staging; fused BN.
    __shared__ unsigned short xs[4 * 728 * 8];
    constexpr int TOT = 4 * 720, NIT = (TOT + TPB - 1) / TPB;  // 12
    ushort8 rA[NIT];
    auto loadChunk = [&](int c0) {
      const unsigned short* sb; int Cs, cl_;
      if (c0 < CA){ sb = inA + (long)n * CA * spin; Cs = CA; cl_ = c0; }
      else        { sb = inB + (long)n * CB * spin; Cs = CB; cl_ = c0 - CA; }
#pragma unroll
      for (int it = 0; it < NIT; ++it) {
        int idx = tid + it * TPB;
        ushort8 v = (ushort8){0,0,0,0,0,0,0,0};
        if (idx < TOT) {
          int q = idx / 720, pt = idx - q * 720;
          int zw = pt % 18; int zt = pt / 18; int zh = zt % 10; int zd = zt / 10;
          int gd = d0 + zd - 1, gh = h0 + zh - 1, gw = w0 + zw - 1;
          if ((unsigned)gd < (unsigned)G && (unsigned)gh < (unsigned)G && (unsigned)gw < (unsigned)G)
            v = *(const ushort8*)(sb + (((long)gd * G + gh) * G + gw) * Cs + cl_ + q * 8);
        }
        rA[it] = v;
      }
    };
    auto writeChunk = [&](int c0) {
      bool useBN; int cl_;
      if (c0 < CA){ useBN = (scA != nullptr); cl_ = c0; }
      else        { useBN = false; cl_ = c0 - CA; }
#pragma unroll
      for (int it = 0; it < NIT; ++it) {
        int idx = tid + it * TPB;
        if (idx < TOT) {
          int q = idx / 720, pt = idx - q * 720;
          ushort8 v = rA[it];
          if (useBN) {
            int zw = pt % 18; int zt = pt / 18; int zh = zt % 10; int zd = zt / 10;
            int gd = d0 + zd - 1, gh = h0 + zh - 1, gw = w0 + zw - 1;
            if ((unsigned)gd < (unsigned)G && (unsigned)gh < (unsigned)G && (unsigned)gw < (unsigned)G)
              v = bnApply8(v, scA, shA, cl_ + q * 8);
          }
          *(ushort8*)(xs + (q * 728 + pt) * 8) = v;
        }
      }
    };

    const int nch = CIP >> 5;
    loadChunk(0);
#pragma unroll 1
    for (int ch = 0; ch < nch; ++ch) {
      int c0 = ch << 5;
      if (ch) __syncthreads();
      writeChunk(c0);
      __syncthreads();
      if (ch + 1 < nch) loadChunk((ch + 1) << 5);
#pragma unroll 1
      for (int a = 0; a < 3; ++a) {
        int zd = wvd + a;
        short8 A0[3][3], A1[3][3];
#pragma unroll
        for (int b = 0; b < 3; ++b)
#pragma unroll
          for (int c = 0; c < 3; ++c) {
            int tap = (a * 3 + b) * 3 + c;
            const unsigned short* ap = wb + ((long)tap * COP + co0 + l15) * CIP + c0 + lg * 8;
            A0[b][c] = *(const short8*)ap;
            if (CO_TILES == 2) A1[b][c] = *(const short8*)(ap + 16 * CIP);
          }
#pragma unroll
        for (int sl = 0; sl < 6; ++sl) {
          int sg = jbase + sl;
          int rb = (lg * 728 + (zd * 10 + sg) * 18 + l15) * 8;
          short8 B0 = *(const short8*)(xs + rb);
          short8 B1 = *(const short8*)(xs + rb + 8);
          short8 B2 = *(const short8*)(xs + rb + 16);
#pragma unroll
          for (int b = 0; b < 3; ++b) {
            int j = sl - b;
            if (j >= 0 && j < 4) {
              acc[0][j] = __builtin_amdgcn_mfma_f32_16x16x32_bf16(A0[b][0], B0, acc[0][j], 0, 0, 0);
              acc[0][j] = __builtin_amdgcn_mfma_f32_16x16x32_bf16(A0[b][1], B1, acc[0][j], 0, 0, 0);
              acc[0][j] = __builtin_amdgcn_mfma_f32_16x16x32_bf16(A0[b][2], B2, acc[0][j], 0, 0, 0);
              if (CO_TILES == 2) {
                acc[1][j] = __builtin_amdgcn_mfma_f32_16x16x32_bf16(A1[b][0], B0, acc[1][j], 0, 0, 0);
                acc[1][j] = __builtin_amdgcn_mfma_f32_16x16x32_bf16(A1[b][1], B1, acc[1][j], 0, 0, 0);
                acc[1][j] = __builtin_amdgcn_mfma_f32_16x16x32_bf16(A1[b][2], B2, acc[1][j], 0, 0, 0);
              }
            }
          }
        }
      }
    }
  } else {
    // VARIANT 2: stride-2 conv, direct-global B (inputs pre-normalized).
    const int nch = CIP >> 5;
#pragma unroll 1
    for (int ch = 0; ch < nch; ++ch) {
      int c0 = ch << 5;
      const unsigned short* src; int Cs, cl_;
      if (c0 < CA){ src = inA; Cs = CA; cl_ = c0; } else { src = inB; Cs = CB; cl_ = c0 - CA; }
      const unsigned short* sb = src + (long)n * Cs * spin;
#pragma unroll 1
      for (int a = 0; a < 3; ++a) {
        int gd = 2 * (d0 + wv) + a - 1;
        bool vd = (unsigned)gd < (unsigned)Gin;
#pragma unroll 1
        for (int b = 0; b < 3; ++b) {
#pragma unroll
          for (int c = 0; c < 3; ++c) {
            int tap = (a * 3 + b) * 3 + c;
            const unsigned short* ap = wb + ((long)tap * COP + co0 + l15) * CIP + c0 + lg * 8;
            short8 A0 = *(const short8*)ap;
            short8 A1;
            if (CO_TILES == 2) A1 = *(const short8*)(ap + 16 * CIP);
            int gw = 2 * (w0 + l15) + c - 1;
            bool vdw = vd && ((unsigned)gw < (unsigned)Gin);
#pragma unroll
            for (int j = 0; j < 4; ++j) {
              int gh = 2 * (h0 + j) + b - 1;
              short8 B = (short8){0,0,0,0,0,0,0,0};
              if (vdw && (unsigned)gh < (unsigned)Gin)
                B = *(const short8*)(sb + (((long)gd * Gin + gh) * Gin + gw) * Cs + cl_ + lg * 8);
              acc[0][j] = __builtin_amdgcn_mfma_f32_16x16x32_bf16(A0, B, acc[0][j], 0, 0, 0);
              if (CO_TILES == 2)
                acc[1][j] = __builtin_amdgcn_mfma_f32_16x16x32_bf16(A1, B, acc[1][j], 0, 0, 0);
            }
          }
        }
      }
    }
  }

  // ---- store ----
  const long spo = (long)G * G * G;
#pragma unroll
  for (int j = 0; j < 4; ++j) {
    long pt;
    if constexpr (VARIANT == 0)
      pt = ((long)(d0 + wvd) * G + (h0 + jbase + j)) * G + (w0 + l15);
    else
      pt = ((long)(d0 + wv) * G + (h0 + j)) * G + (w0 + l15);
    if constexpr (!FOUT) {
      unsigned short* outp = (unsigned short*)outv;
#pragma unroll
      for (int ct = 0; ct < CO_TILES; ++ct) {
        ushort4v pk;
#pragma unroll
        for (int r = 0; r < 4; ++r) pk[r] = f2b(acc[ct][j][r]);
        *(ushort4v*)(outp + ((long)n * spo + pt) * Cout + co0 + ct * 16 + lg * 4) = pk;
      }
    } else {
      float* outp = (float*)outv;
#pragma unroll
      for (int ct = 0; ct < CO_TILES; ++ct)
#pragma unroll
        for (int r = 0; r < 4; ++r) {
          int co = co0 + ct * 16 + lg * 4 + r;
          if (co < Cout) outp[((long)(n * Cout + co)) * spo + pt] = acc[ct][j][r];
        }
    }
  }
}

// ---------------- BN stats stage 1 (channels-last, raw tensor) ----------------
__global__ void bn_stats1_cl(const unsigned short* __restrict__ x, float* __restrict__ part,
                             long npts, int C, int lC, int K){
  int chunk = blockIdx.x, tid = threadIdx.x;
  int c = tid & (C - 1); int pr = tid >> lC; int PR = TPB >> lC;
  float s = 0.f, q = 0.f;
  for (long p = (long)chunk * PR + pr; p < npts; p += (long)K * PR) {
    float f = b2f(x[p * C + c]); s += f; q += f * f;
  }
  __shared__ float shs[TPB], shq[TPB];
  shs[tid] = s; shq[tid] = q;
  __syncthreads();
  for (int off = TPB / 2; off >= C; off >>= 1) {
    if (tid < off) { shs[tid] += shs[tid + off]; shq[tid] += shq[tid + off]; }
    __syncthreads();
  }
  if (tid < C) { part[((long)tid * K + chunk) * 2] = shs[tid]; part[((long)tid * K + chunk) * 2 + 1] = shq[tid]; }
}

// ---------------- BN stats stage 2 -> scale/shift ----------------
__global__ void bn_stats2_k(const float* __restrict__ part, const float* __restrict__ g,
                            const float* __restrict__ b, float* __restrict__ scale,
                            float* __restrict__ shift, int C, int K, float inv_cnt) {
  int c = blockIdx.x * blockDim.x + threadIdx.x;
  if (c >= C) return;
  float s = 0.f, q = 0.f;
  for (int k = 0; k < K; ++k) { s += part[((long)c * K + k) * 2]; q += part[((long)c * K + k) * 2 + 1]; }
  float m = s * inv_cnt, v = q * inv_cnt - m * m;
  float rs = rsqrtf(v + 1e-5f) * g[c];
  scale[c] = rs;
  shift[c] = b[c] - m * rs;
}

// ---------------- BN apply + ReLU pass (for s1, s2 only) ----------------
__global__ void bn_relu_cl(unsigned short* __restrict__ x, const float* __restrict__ sc,
                           const float* __restrict__ sh, int C, long tot8){
  long i8 = (long)blockIdx.x * TPB + threadIdx.x;
  if (i8 >= tot8) return;
  long e = i8 * 8;
  int c0 = (int)(e & (C - 1));
  ushort8 v = *(ushort8*)(x + e);
  *(ushort8*)(x + e) = bnApply8(v, sc, sh, c0);
}

extern "C" void kernel_launch(void* const* d_in, const int* in_sizes, int n_in,
                              void* d_out, int out_size, void* d_ws, size_t ws_size,
                              hipStream_t stream) {
  const float* x    = (const float*)d_in[0];
  const float* w0   = (const float*)d_in[1];
  const float* g0   = (const float*)d_in[2];
  const float* b0   = (const float*)d_in[3];
  const float* w1   = (const float*)d_in[4];
  const float* g1   = (const float*)d_in[5];
  const float* b1   = (const float*)d_in[6];
  const float* w2   = (const float*)d_in[7];
  const float* g2   = (const float*)d_in[8];
  const float* b2   = (const float*)d_in[9];
  const float* wt2r = (const float*)d_in[10];
  const float* g2r  = (const float*)d_in[11];
  const float* b2r  = (const float*)d_in[12];
  const float* wt1r = (const float*)d_in[13];
  const float* g1r  = (const float*)d_in[14];
  const float* b1r  = (const float*)d_in[15];
  const float* wt0r = (const float*)d_in[16];
  const float* wt2c = (const float*)d_in[17];
  const float* g2c  = (const float*)d_in[18];
  const float* b2c  = (const float*)d_in[19];
  const float* wt1c = (const float*)d_in[20];
  const float* g1c  = (const float*)d_in[21];
  const float* b1c  = (const float*)d_in[22];
  const float* wt0c = (const float*)d_in[23];

  const int N = 2;
  const long sp64 = 262144, sp32 = 32768, sp16 = 4096;
  const int K = 256;  // bn chunks

  // ---- workspace (ushort units), all activations NDHWC bf16 ----
  unsigned short* W = (unsigned short*)d_ws;
  unsigned short* s1   = W;                       // [2*sp64][32]
  unsigned short* s2   = s1  + 16777216;          // [2*sp32][64]
  unsigned short* s4   = s2  + 4194304;           // [2*sp16][128]
  unsigned short* r32  = s4  + 1048576;           // [2*sp32][64]
  unsigned short* c32  = r32 + 4194304;           // [2*sp32][64]
  unsigned short* r64  = c32 + 4194304;           // [2*sp64][32]
  unsigned short* xt   = r64;                     // alias (dead after conv0)
  unsigned short* c64  = r64 + 16777216;          // [2*sp64][64]
  unsigned short* wb0p = c64 + 33554432;          // 14*32*32
  unsigned short* wb1  = wb0p + 14336;            // 27*64*32
  unsigned short* wb2  = wb1  + 55296;            // 27*128*64
  unsigned short* wb2r = wb2  + 221184;           // 27*64*128
  unsigned short* wb2c = wb2r + 221184;
  unsigned short* wb1r = wb2c + 221184;           // 27*32*64
  unsigned short* wb1c = wb1r + 55296;            // 27*64*128
  unsigned short* wbrec= wb1c + 221184;           // 27*16*32
  unsigned short* wbcl = wbrec+ 13824;            // 27*16*96
  float* part = (float*)(wbcl + 41472);
  float* bsc  = part + 128L * K * 2;              // shared (s1, s2)
  float* bsh  = bsc + 128;
  float* sc_s4  = bsh  + 128; float* sh_s4  = sc_s4  + 128;
  float* sc_r32 = sh_s4 + 128; float* sh_r32 = sc_r32 + 128;
  float* sc_c32 = sh_r32+ 128; float* sh_c32 = sc_c32 + 128;
  float* sc_r64 = sh_c32+ 128; float* sh_r64 = sc_r64 + 128;
  float* sc_c64 = sh_r64+ 128; float* sh_c64 = sc_c64 + 128;

  float* out_cl  = (float*)d_out;                 // [2][2][64^3] NCDHW
  float* out_rec = (float*)d_out + 2L * 2 * sp64; // [2][16][64^3]

  // ---- weight repacks ----
  rp_pair<<<cdiv_l(14L*32*32, TPB), TPB, 0, stream>>>(w0, wb0p);
  rp_enc<<<cdiv_l(27L*64*32, TPB), TPB, 0, stream>>>(w1, wb1, 32, 64);
  rp_enc<<<cdiv_l(27L*128*64, TPB), TPB, 0, stream>>>(w2, wb2, 64, 128);
  rp_dec<<<cdiv_l(27L*64*128, TPB), TPB, 0, stream>>>(wt2r, wb2r, 128, 64, 128, 64);
  rp_dec<<<cdiv_l(27L*64*128, TPB), TPB, 0, stream>>>(wt2c, wb2c, 128, 64, 128, 64);
  rp_dec<<<cdiv_l(27L*32*64, TPB), TPB, 0, stream>>>(wt1r, wb1r, 64, 32, 64, 32);
  rp_dec<<<cdiv_l(27L*64*128, TPB), TPB, 0, stream>>>(wt1c, wb1c, 128, 64, 128, 64);
  rp_dec<<<cdiv_l(27L*16*32, TPB), TPB, 0, stream>>>(wt0r, wbrec, 32, 16, 32, 16);
  rp_dec<<<cdiv_l(27L*16*96, TPB), TPB, 0, stream>>>(wt0c, wbcl, 96, 2, 96, 16);

  // ---- x -> NDHWC bf16 ----
  xpose_k<<<2048, TPB, 0, stream>>>(x, xt);

  auto bnStats = [&](unsigned short* t, const float* g, const float* b, int C, int lC,
                     long npts, float* sc, float* sh) {
    bn_stats1_cl<<<K, TPB, 0, stream>>>(t, part, npts, C, lC, K);
    bn_stats2_k<<<1, 128, 0, stream>>>(part, g, b, sc, sh, C, K, 1.f / (float)(npts));
  };
  auto bnFull = [&](unsigned short* t, const float* g, const float* b, int C, int lC, long npts) {
    bnStats(t, g, b, C, lC, npts, bsc, bsh);
    long tot8 = npts * C / 8;
    bn_relu_cl<<<cdiv_l(tot8, TPB), TPB, 0, stream>>>(t, bsc, bsh, C, tot8);
  };

  auto gx0 = [&](int G){ return (unsigned)(N * (G >> 1) * (G >> 3) * (G >> 4)); };
  auto gx  = [&](int G){ return (unsigned)(N * (G >> 2) * (G >> 2) * (G >> 4)); };

  // ---- encoder ----
  mconv<0, 2, true, false><<<dim3(gx0(64), 1), TPB, 0, stream>>>(
      xt, 16, nullptr, 0, nullptr, nullptr, wb0p, s1, N, 32, 32, 32, 64);
  bnFull(s1, g0, b0, 32, 5, 2 * sp64);
  mconv<2, 2, false, false><<<dim3(gx(32), 2), TPB, 0, stream>>>(
      s1, 32, nullptr, 0, nullptr, nullptr, wb1, s2, N, 64, 64, 32, 32);
  bnFull(s2, g1, b1, 64, 6, 2 * sp32);
  mconv<2, 1, false, false><<<dim3(gx(16), 8), TPB, 0, stream>>>(
      s2, 64, nullptr, 0, nullptr, nullptr, wb2, s4, N, 128, 128, 64, 16);
  bnStats(s4, g2, b2, 128, 7, 2 * sp16, sc_s4, sh_s4);

  // ---- level-2 tconvs (16 -> 32), quadrants; BN(s4) fused on load ----
  tconv_quad<2><<<dim3(gx(16), 2, 4), TPB, 0, stream>>>(
      s4, 128, nullptr, 0, sc_s4, sh_s4, wb2r, r32, N, 64, 64, 128, 16);
  bnStats(r32, g2r, b2r, 64, 6, 2 * sp32, sc_r32, sh_r32);
  tconv_quad<2><<<dim3(gx(16), 2, 4), TPB, 0, stream>>>(
      s4, 128, nullptr, 0, sc_s4, sh_s4, wb2c, c32, N, 64, 64, 128, 16);
  bnStats(c32, g2c, b2c, 64, 6, 2 * sp32, sc_c32, sh_c32);

  // ---- level-1 tconvs (32 -> 64), quadrants ----
  tconv_quad<2><<<dim3(gx(32), 1, 4), TPB, 0, stream>>>(
      r32, 64, nullptr, 0, sc_r32, sh_r32, wb1r, r64, N, 32, 32, 64, 32);
  bnStats(r64, g1r, b1r, 32, 5, 2 * sp64, sc_r64, sh_r64);
  tconv_quad<2><<<dim3(gx(32), 2, 4), TPB, 0, stream>>>(
      c32, 64, s2, 64, sc_c32, sh_c32, wb1c, c64, N, 64, 64, 128, 32);
  bnStats(c64, g1c, b1c, 64, 6, 2 * sp64, sc_c64, sh_c64);

  // ---- level-0 stride-1 convs (no BN on output), fused BN on inputs ----
  mconv<0, 1, false, true><<<dim3(gx0(64), 1), TPB, 0, stream>>>(
      r64, 32, nullptr, 0, sc_r64, sh_r64, wbrec, out_rec, N, 16, 16, 32, 64);
  mconv<0, 1, false, true><<<dim3(gx0(64), 1), TPB, 0, stream>>>(
      c64, 64, s1, 32, sc_c64, sh_c64, wbcl, out_cl, N, 2, 16, 96, 64);
}